// Round 1
// 346.445 us; speedup vs baseline: 1.0245x; 1.0245x over previous
//
#include <hip/hip_runtime.h>
#include <math.h>

// Twist (axis-angle) -> rotation matrix, Rodrigues formula.
// Input:  [8388608, 3] f32 ; Output: [8388608, 3, 3] f32.
// Memory-bound streaming: 100.7 MB read + 302 MB write, floor ~64 us.
//
// v3: 1 rotation/thread, tiny LDS (9.125 KB) -> 8 blocks/CU, 32 waves/CU
// (full occupancy, was 16 waves at 36 KB). Theory: the 4-phase barrier
// structure needs many independent blocks per CU to keep HBM saturated in
// both directions; v2b's 4 blocks/CU ran at ~2.4 TB/s effective while the
// harness's own fill proves 6.4 TB/s is reachable.
// LDS phases are conflict-free by construction: word indices 3*tid+j and
// 9*tid+j are bijective mod 32 banks (3, 9 coprime with 32 -> 2 lanes/bank,
// free on wave64); bulk phases stay linear dwordx4.

typedef float v4f __attribute__((ext_vector_type(4)));

#define TPB 256
#define RPB TPB                   // 1 rotation per thread
#define IN_F4 (RPB * 3 / 4)       // 192  v4f in  per block (3 KB)
#define OUT_F4 (RPB * 9 / 4)      // 576  v4f out per block (9 KB)

__global__ __launch_bounds__(TPB, 8) void twist2mat_kernel(
    const v4f* __restrict__ in4, v4f* __restrict__ out4) {
    const int tid = threadIdx.x;
    const int bin  = blockIdx.x * IN_F4;
    const int bout = blockIdx.x * OUT_F4;

    __shared__ v4f buf[OUT_F4];          // 9.125 KB incl. nothing extra
    float* fbuf = (float*)buf;

    // Phase 1: coalesced global->LDS (first 192 lanes, 1 dwordx4 each).
    if (tid < IN_F4)
        buf[tid] = __builtin_nontemporal_load(&in4[bin + tid]);
    __syncthreads();

    // Phase 2: this thread's rotation (3 floats). Banks: (3*tid+j) % 32,
    // 3 coprime 32 -> exactly 2 lanes/bank per access -> conflict-free.
    const float w0 = fbuf[3 * tid + 0];
    const float w1 = fbuf[3 * tid + 1];
    const float w2 = fbuf[3 * tid + 2];
    __syncthreads();   // all reads done before buf is reused for output

    const float n2  = fmaf(w0, w0, fmaf(w1, w1, w2 * w2));
    const float t   = fmaxf(sqrtf(n2), 1e-5f);   // clamp(||w||, 1e-5)
    const float inv = 1.0f / t;
    const float a0 = w0 * inv, a1 = w1 * inv, a2 = w2 * inv;
    float s, c;
    __sincosf(t, &s, &c);
    const float c1 = 1.0f - c;
    // AA = a a^T - (a.a) I  (exact A@A for the clamped non-unit case).
    const float aa = fmaf(a0, a0, fmaf(a1, a1, a2 * a2));
    float r[9];
    r[0] = fmaf(c1, fmaf(a0, a0, -aa), 1.0f);
    r[1] = fmaf(c1, a0 * a1, -s * a2);
    r[2] = fmaf(c1, a0 * a2,  s * a1);
    r[3] = fmaf(c1, a0 * a1,  s * a2);
    r[4] = fmaf(c1, fmaf(a1, a1, -aa), 1.0f);
    r[5] = fmaf(c1, a1 * a2, -s * a0);
    r[6] = fmaf(c1, a0 * a2, -s * a1);
    r[7] = fmaf(c1, a1 * a2,  s * a0);
    r[8] = fmaf(c1, fmaf(a2, a2, -aa), 1.0f);

    // Phase 3: registers -> LDS in output-linear order. Banks: (9*tid+j)%32,
    // 9 coprime 32 -> 2 lanes/bank -> conflict-free.
#pragma unroll
    for (int k = 0; k < 9; ++k)
        fbuf[9 * tid + k] = r[k];
    __syncthreads();

    // Phase 4: coalesced LDS->global, nontemporal dwordx4 (pure streaming).
    // 576 chunks = 2 full rounds + 64-lane tail.
    __builtin_nontemporal_store(buf[tid          ], &out4[bout + tid          ]);
    __builtin_nontemporal_store(buf[tid + TPB    ], &out4[bout + tid + TPB    ]);
    if (tid < OUT_F4 - 2 * TPB)   // 64
        __builtin_nontemporal_store(buf[tid + 2 * TPB],
                                    &out4[bout + tid + 2 * TPB]);
}

extern "C" void kernel_launch(void* const* d_in, const int* in_sizes, int n_in,
                              void* d_out, int out_size, void* d_ws, size_t ws_size,
                              hipStream_t stream) {
    (void)n_in; (void)out_size; (void)d_ws; (void)ws_size;
    const v4f* in4 = (const v4f*)d_in[0];
    v4f* out4 = (v4f*)d_out;
    const int nrot = in_sizes[0] / 3;       // 8,388,608
    const int grid = nrot / RPB;            // exact: 32768 blocks
    twist2mat_kernel<<<grid, TPB, 0, stream>>>(in4, out4);
}